// Round 3
// baseline (1262.021 us; speedup 1.0000x reference)
//
#include <hip/hip_runtime.h>
#include <cstddef>

#define NB 32
#define NC 4
#define NH 512
#define NW 512
#define PLANE (NH * NW)
#define NSTEPS 8
#define GBLK 32                 // blocks per batch (one barrier group)
#define SROWS (NH / GBLK)       // 16 rows per strip
#define NBLOCKS (NB * GBLK)     // 1024 blocks = 4/CU on 256 CUs -> all resident

typedef float v4f __attribute__((ext_vector_type(4)));

// Block-wide (256-thread) sum reduction. Valid result only in threadIdx.x==0.
__device__ __forceinline__ float blockReduce256(float v, float* sm) {
#pragma unroll
    for (int off = 32; off > 0; off >>= 1) v += __shfl_down(v, off, 64);
    int lane = threadIdx.x & 63;
    int wave = threadIdx.x >> 6;
    if (lane == 0) sm[wave] = v;
    __syncthreads();
    float r = (threadIdx.x == 0) ? ((sm[0] + sm[1]) + (sm[2] + sm[3])) : 0.0f;
    __syncthreads();            // sm is reused by later reductions
    return r;
}

// Barrier among the GBLK blocks of one batch. Monotonic counter, no reset.
// __syncthreads drains each wave's stores to L2; __threadfence emits the
// gfx950 agent-scope writeback/invalidate so strip halos + partial sums are
// visible across XCDs (G16). All 1024 blocks are co-resident (4/CU), so the
// spin cannot deadlock.
__device__ __forceinline__ void groupBarrier(unsigned* bar, int tgt) {
    __syncthreads();
    __threadfence();
    if (threadIdx.x == 0) {
        __hip_atomic_fetch_add(bar, 1u, __ATOMIC_ACQ_REL, __HIP_MEMORY_SCOPE_AGENT);
        while (__hip_atomic_load(bar, __ATOMIC_ACQUIRE, __HIP_MEMORY_SCOPE_AGENT) <
               (unsigned)tgt)
            __builtin_amdgcn_s_sleep(2);
    }
    __syncthreads();
    __threadfence();
}

// One kernel for the whole op. Block (b, s) owns strip s of batch b forever.
// Phase A: strip sums of all 4 channels + nontemporal copy of ch1..3 (and ch0
//          for t==0 batches, whose result IS the input). Partials go to
//          private slots — no atomics, no memset dependency.
// Phase B: t[b] steps, separated by per-batch groupBarrier. Active steps for
//          batch b are exactly i < t[b] (mask is a prefix; masked steps are
//          bitwise identity). Final step writes directly to out ch0.
__global__ __launch_bounds__(256, 4) void fused_kernel(
    const float* __restrict__ x, float* __restrict__ out, float* __restrict__ ws,
    float* __restrict__ partA,      // [NB][3][GBLK] ch1..3 strip partials
    float* __restrict__ stepPart,   // [NSTEPS][NB][GBLK] ch0 strip partials
    unsigned* __restrict__ bar,     // [NB] monotonic barrier counters (zeroed)
    const float* __restrict__ Wm, const float* __restrict__ bv,
    const int* __restrict__ tg) {
    __shared__ float sm[4];
    __shared__ float prm[2];
    int b = blockIdx.x >> 5;        // batch
    int s = blockIdx.x & 31;        // strip
    int tb = tg[b];

    const size_t xb = (size_t)b * NC * PLANE;
    const int rows0 = s * SROWS;
    const int nvec = SROWS * NW / 4;    // 2048 float4 per strip

    // ---------- Phase A ----------
    {
        const v4f* s4 = (const v4f*)(x + xb + (size_t)rows0 * NW);
        v4f* d4 = (v4f*)(out + xb + (size_t)rows0 * NW);
        float a0 = 0.0f;
        if (tb == 0) {
            for (int j = threadIdx.x; j < nvec; j += 256) {
                v4f v = s4[j];
                a0 += (v.x + v.y) + (v.z + v.w);
                __builtin_nontemporal_store(v, &d4[j]);   // final result = input
            }
        } else {
            for (int j = threadIdx.x; j < nvec; j += 256) {
                v4f v = s4[j];                             // re-read by step 0
                a0 += (v.x + v.y) + (v.z + v.w);
            }
        }
        float a123[3];
#pragma unroll
        for (int c = 1; c < 4; ++c) {
            const v4f* sc = (const v4f*)(x + xb + (size_t)c * PLANE + (size_t)rows0 * NW);
            v4f* dc = (v4f*)(out + xb + (size_t)c * PLANE + (size_t)rows0 * NW);
            float a = 0.0f;
            for (int j = threadIdx.x; j < nvec; j += 256) {
                v4f v = __builtin_nontemporal_load(&sc[j]);
                a += (v.x + v.y) + (v.z + v.w);
                __builtin_nontemporal_store(v, &dc[j]);
            }
            a123[c - 1] = a;
        }
        float t0 = blockReduce256(a0, sm);
        float t1 = blockReduce256(a123[0], sm);
        float t2 = blockReduce256(a123[1], sm);
        float t3 = blockReduce256(a123[2], sm);
        if (threadIdx.x == 0) {
            stepPart[b * GBLK + s] = t0;                   // step-0 ch0 partial
            partA[(b * 3 + 0) * GBLK + s] = t1;
            partA[(b * 3 + 1) * GBLK + s] = t2;
            partA[(b * 3 + 2) * GBLK + s] = t3;
        }
    }
    if (tb == 0) return;

    int syncs = 1;
    groupBarrier(&bar[b], GBLK * syncs);

    // ---------- Phase B ----------
    for (int i = 0; i < tb; ++i) {
        // D, rho from the batch mean (wave 0 reduces the 32 strip partials).
        if (threadIdx.x < 64) {
            int l = threadIdx.x & 31;
            float f0 = stepPart[(i * NB + b) * GBLK + l];
            float f1 = partA[(b * 3 + 0) * GBLK + l];
            float f2 = partA[(b * 3 + 1) * GBLK + l];
            float f3 = partA[(b * 3 + 2) * GBLK + l];
#pragma unroll
            for (int off = 16; off > 0; off >>= 1) {
                f0 += __shfl_down(f0, off, 32);
                f1 += __shfl_down(f1, off, 32);
                f2 += __shfl_down(f2, off, 32);
                f3 += __shfl_down(f3, off, 32);
            }
            if (threadIdx.x == 0) {
                const float inv = 1.0f / (float)PLANE;
                f0 *= inv; f1 *= inv; f2 *= inv; f3 *= inv;
                float z0 = f0 * Wm[0] + f1 * Wm[2] + f2 * Wm[4] + f3 * Wm[6] + bv[0];
                float z1 = f0 * Wm[1] + f1 * Wm[3] + f2 * Wm[5] + f3 * Wm[7] + bv[1];
                prm[0] = 0.2f / (1.0f + expf(-z0));        // D
                prm[1] = 0.1f / (1.0f + expf(-z1));        // rho
            }
        }
        __syncthreads();
        float D = prm[0], rho = prm[1];

        const float* sp = (i == 0) ? (x + xb)
                        : (i & 1)  ? (ws + (size_t)b * PLANE)
                                   : (out + xb);
        bool fin = (i == tb - 1);
        float* dp = (fin || (i & 1)) ? (out + xb) : (ws + (size_t)b * PLANE);

        // 16-row strip, 8 rows/thread, rolling 3-row register window.
        int col4 = threadIdx.x & 127;
        int x0 = col4 * 4;
        int half = threadIdx.x >> 7;
        int lane = threadIdx.x & 63;
        int y0 = rows0 + half * (SROWS / 2);

        v4f up = ((const v4f*)(sp + (size_t)((y0 - 1) & (NH - 1)) * NW))[col4];
        v4f cc = ((const v4f*)(sp + (size_t)y0 * NW))[col4];
        float acc = 0.0f;
#pragma unroll
        for (int k = 0; k < SROWS / 2; ++k) {
            int y = y0 + k;
            v4f dn = ((const v4f*)(sp + (size_t)((y + 1) & (NH - 1)) * NW))[col4];
            // Row halos: col4 = lane + 64*w is consecutive within a wave.
            float lft = __shfl_up(cc.w, 1, 64);
            if (lane == 0) lft = sp[(size_t)y * NW + ((x0 - 1) & (NW - 1))];
            float rgt = __shfl_down(cc.x, 1, 64);
            if (lane == 63) rgt = sp[(size_t)y * NW + ((x0 + 4) & (NW - 1))];
            v4f un;
            un.x = cc.x + (D * (up.x + dn.x + lft + cc.y - 4.0f * cc.x) + rho * cc.x * (1.0f - cc.x));
            un.y = cc.y + (D * (up.y + dn.y + cc.x + cc.z - 4.0f * cc.y) + rho * cc.y * (1.0f - cc.y));
            un.z = cc.z + (D * (up.z + dn.z + cc.y + cc.w - 4.0f * cc.z) + rho * cc.z * (1.0f - cc.z));
            un.w = cc.w + (D * (up.w + dn.w + cc.z + rgt - 4.0f * cc.w) + rho * cc.w * (1.0f - cc.w));
            if (fin) __builtin_nontemporal_store(un, &((v4f*)(dp + (size_t)y * NW))[col4]);
            else ((v4f*)(dp + (size_t)y * NW))[col4] = un;
            acc += (un.x + un.y) + (un.z + un.w);
            up = cc; cc = dn;
        }

        if (!fin) {
            float tot = blockReduce256(acc, sm);
            if (threadIdx.x == 0) stepPart[((i + 1) * NB + b) * GBLK + s] = tot;
            ++syncs;
            groupBarrier(&bar[b], GBLK * syncs);
        }
    }
}

extern "C" void kernel_launch(void* const* d_in, const int* in_sizes, int n_in,
                              void* d_out, int out_size, void* d_ws, size_t ws_size,
                              hipStream_t stream) {
    const float* x = (const float*)d_in[0];
    const float* Wm = (const float*)d_in[1];
    const float* bv = (const float*)d_in[2];
    const int* t = (const int*)d_in[3];
    float* out = (float*)d_out;

    // ws layout: [u ping-pong: NB*PLANE f][partA: NB*3*GBLK f]
    //            [stepPart: NSTEPS*NB*GBLK f][bar: NB u32]
    float* wsU = (float*)d_ws;
    float* partA = wsU + (size_t)NB * PLANE;
    float* stepPart = partA + NB * 3 * GBLK;
    unsigned* bar = (unsigned*)(stepPart + NSTEPS * NB * GBLK);

    // Only the barrier counters need zeroing (ws is poisoned each call);
    // every partial-sum slot is written before it is read.
    hipMemsetAsync(bar, 0, sizeof(unsigned) * NB, stream);

    fused_kernel<<<NBLOCKS, 256, 0, stream>>>(x, out, wsU, partA, stepPart, bar,
                                              Wm, bv, t);
}

// Round 5
// 651.416 us; speedup vs baseline: 1.9373x; 1.9373x over previous
//
#include <hip/hip_runtime.h>
#include <cstddef>

#define NB 32
#define NC 4
#define NH 512
#define NW 512
#define PLANE (NH * NW)
#define NSTEPS 8
#define GBLK 32                 // blocks per batch (one barrier group)
#define SROWS (NH / GBLK)       // 16 rows per strip
#define NBLOCKS (NB * GBLK)     // 1024 blocks = 4/CU on 256 CUs -> all resident

typedef float v4f __attribute__((ext_vector_type(4)));

// Block-wide (256-thread) sum reduction. Valid result only in threadIdx.x==0.
__device__ __forceinline__ float blockReduce256(float v, float* sm) {
#pragma unroll
    for (int off = 32; off > 0; off >>= 1) v += __shfl_down(v, off, 64);
    int lane = threadIdx.x & 63;
    int wave = threadIdx.x >> 6;
    if (lane == 0) sm[wave] = v;
    __syncthreads();
    float r = (threadIdx.x == 0) ? ((sm[0] + sm[1]) + (sm[2] + sm[3])) : 0.0f;
    __syncthreads();            // sm is reused by later reductions
    return r;
}

// Barrier among the GBLK blocks of one batch.
// Round-3 lesson: agent-scope ACQUIRE per poll = L1/L2 invalidate per poll =
// invalidation storm (307 GB/s, VALUBusy 0.9%). Protocol now:
//   release: __syncthreads drains all waves' stores to the XCD L2; thread 0's
//            RELEASE fence writes back the local L2 ONCE (covers every wave's
//            stores); RELAXED fetch_add publishes.
//   spin:    RELAXED atomic loads (coherence-point access, no invalidates).
//   acquire: after the counter trips, one ACQUIRE fence (invalidate only)
//            before reading halos.
// All 1024 blocks are co-resident (4/CU), so the spin cannot deadlock.
__device__ __forceinline__ void groupBarrier(unsigned* bar, unsigned tgt) {
    __syncthreads();
    if (threadIdx.x == 0) {
        __builtin_amdgcn_fence(__ATOMIC_RELEASE, "agent");
        __hip_atomic_fetch_add(bar, 1u, __ATOMIC_RELAXED, __HIP_MEMORY_SCOPE_AGENT);
        unsigned v;
        do {
            v = __hip_atomic_load(bar, __ATOMIC_RELAXED, __HIP_MEMORY_SCOPE_AGENT);
            if (v < tgt) __builtin_amdgcn_s_sleep(4);
        } while (v < tgt);
    }
    __syncthreads();
    __builtin_amdgcn_fence(__ATOMIC_ACQUIRE, "agent");
}

// One kernel for the whole op. Block (b, s) owns strip s of batch b forever.
// Phase A: strip sums of all 4 channels + nontemporal copy of ch1..3 (and ch0
//          for t==0 batches, whose result IS the input). Partials go to
//          private slots — no atomics, no memset dependency.
// Phase B: t[b] steps, separated by per-batch groupBarrier. Active steps for
//          batch b are exactly i < t[b] (mask is a prefix; masked steps are
//          bitwise identity). Final step writes directly to out ch0.
__global__ __launch_bounds__(256, 4) void fused_kernel(
    const float* __restrict__ x, float* __restrict__ out, float* __restrict__ ws,
    float* __restrict__ partA,      // [NB][3][GBLK] ch1..3 strip partials
    float* __restrict__ stepPart,   // [NSTEPS][NB][GBLK] ch0 strip partials
    unsigned* __restrict__ bar,     // [NB] monotonic barrier counters (zeroed)
    const float* __restrict__ Wm, const float* __restrict__ bv,
    const int* __restrict__ tg) {
    __shared__ float sm[4];
    __shared__ float prm[2];
    int b = blockIdx.x >> 5;        // batch
    int s = blockIdx.x & 31;        // strip
    int tb = tg[b];

    const size_t xb = (size_t)b * NC * PLANE;
    const int rows0 = s * SROWS;
    const int nvec = SROWS * NW / 4;    // 2048 float4 per strip

    // ---------- Phase A ----------
    {
        const v4f* s4 = (const v4f*)(x + xb + (size_t)rows0 * NW);
        v4f* d4 = (v4f*)(out + xb + (size_t)rows0 * NW);
        float a0 = 0.0f;
        if (tb == 0) {
            for (int j = threadIdx.x; j < nvec; j += 256) {
                v4f v = s4[j];
                a0 += (v.x + v.y) + (v.z + v.w);
                __builtin_nontemporal_store(v, &d4[j]);   // final result = input
            }
        } else {
            for (int j = threadIdx.x; j < nvec; j += 256) {
                v4f v = s4[j];                             // re-read by step 0
                a0 += (v.x + v.y) + (v.z + v.w);
            }
        }
        float a123[3];
#pragma unroll
        for (int c = 1; c < 4; ++c) {
            const v4f* sc = (const v4f*)(x + xb + (size_t)c * PLANE + (size_t)rows0 * NW);
            v4f* dc = (v4f*)(out + xb + (size_t)c * PLANE + (size_t)rows0 * NW);
            float a = 0.0f;
            for (int j = threadIdx.x; j < nvec; j += 256) {
                v4f v = __builtin_nontemporal_load(&sc[j]);
                a += (v.x + v.y) + (v.z + v.w);
                __builtin_nontemporal_store(v, &dc[j]);
            }
            a123[c - 1] = a;
        }
        float t0 = blockReduce256(a0, sm);
        float t1 = blockReduce256(a123[0], sm);
        float t2 = blockReduce256(a123[1], sm);
        float t3 = blockReduce256(a123[2], sm);
        if (threadIdx.x == 0) {
            stepPart[b * GBLK + s] = t0;                   // step-0 ch0 partial
            partA[(b * 3 + 0) * GBLK + s] = t1;
            partA[(b * 3 + 1) * GBLK + s] = t2;
            partA[(b * 3 + 2) * GBLK + s] = t3;
        }
    }
    if (tb == 0) return;

    unsigned syncs = 1;
    groupBarrier(&bar[b], GBLK * syncs);

    // ---------- Phase B ----------
    for (int i = 0; i < tb; ++i) {
        // D, rho from the batch mean (wave 0 reduces the 32 strip partials).
        if (threadIdx.x < 64) {
            int l = threadIdx.x & 31;
            float f0 = stepPart[(i * NB + b) * GBLK + l];
            float f1 = partA[(b * 3 + 0) * GBLK + l];
            float f2 = partA[(b * 3 + 1) * GBLK + l];
            float f3 = partA[(b * 3 + 2) * GBLK + l];
#pragma unroll
            for (int off = 16; off > 0; off >>= 1) {
                f0 += __shfl_down(f0, off, 32);
                f1 += __shfl_down(f1, off, 32);
                f2 += __shfl_down(f2, off, 32);
                f3 += __shfl_down(f3, off, 32);
            }
            if (threadIdx.x == 0) {
                const float inv = 1.0f / (float)PLANE;
                f0 *= inv; f1 *= inv; f2 *= inv; f3 *= inv;
                float z0 = f0 * Wm[0] + f1 * Wm[2] + f2 * Wm[4] + f3 * Wm[6] + bv[0];
                float z1 = f0 * Wm[1] + f1 * Wm[3] + f2 * Wm[5] + f3 * Wm[7] + bv[1];
                prm[0] = 0.2f / (1.0f + expf(-z0));        // D
                prm[1] = 0.1f / (1.0f + expf(-z1));        // rho
            }
        }
        __syncthreads();
        float D = prm[0], rho = prm[1];

        const float* sp = (i == 0) ? (x + xb)
                        : (i & 1)  ? (ws + (size_t)b * PLANE)
                                   : (out + xb);
        bool fin = (i == tb - 1);
        float* dp = (fin || (i & 1)) ? (out + xb) : (ws + (size_t)b * PLANE);

        // 16-row strip, 8 rows/thread, rolling 3-row register window.
        int col4 = threadIdx.x & 127;
        int x0 = col4 * 4;
        int half = threadIdx.x >> 7;
        int lane = threadIdx.x & 63;
        int y0 = rows0 + half * (SROWS / 2);

        v4f up = ((const v4f*)(sp + (size_t)((y0 - 1) & (NH - 1)) * NW))[col4];
        v4f cc = ((const v4f*)(sp + (size_t)y0 * NW))[col4];
        float acc = 0.0f;
#pragma unroll
        for (int k = 0; k < SROWS / 2; ++k) {
            int y = y0 + k;
            v4f dn = ((const v4f*)(sp + (size_t)((y + 1) & (NH - 1)) * NW))[col4];
            // Row halos: col4 = lane + 64*w is consecutive within a wave.
            float lft = __shfl_up(cc.w, 1, 64);
            if (lane == 0) lft = sp[(size_t)y * NW + ((x0 - 1) & (NW - 1))];
            float rgt = __shfl_down(cc.x, 1, 64);
            if (lane == 63) rgt = sp[(size_t)y * NW + ((x0 + 4) & (NW - 1))];
            v4f un;
            un.x = cc.x + (D * (up.x + dn.x + lft + cc.y - 4.0f * cc.x) + rho * cc.x * (1.0f - cc.x));
            un.y = cc.y + (D * (up.y + dn.y + cc.x + cc.z - 4.0f * cc.y) + rho * cc.y * (1.0f - cc.y));
            un.z = cc.z + (D * (up.z + dn.z + cc.y + cc.w - 4.0f * cc.z) + rho * cc.z * (1.0f - cc.z));
            un.w = cc.w + (D * (up.w + dn.w + cc.z + rgt - 4.0f * cc.w) + rho * cc.w * (1.0f - cc.w));
            if (fin) __builtin_nontemporal_store(un, &((v4f*)(dp + (size_t)y * NW))[col4]);
            else ((v4f*)(dp + (size_t)y * NW))[col4] = un;
            acc += (un.x + un.y) + (un.z + un.w);
            up = cc; cc = dn;
        }

        if (!fin) {
            float tot = blockReduce256(acc, sm);
            if (threadIdx.x == 0) stepPart[((i + 1) * NB + b) * GBLK + s] = tot;
            ++syncs;
            groupBarrier(&bar[b], GBLK * syncs);
        }
    }
}

extern "C" void kernel_launch(void* const* d_in, const int* in_sizes, int n_in,
                              void* d_out, int out_size, void* d_ws, size_t ws_size,
                              hipStream_t stream) {
    const float* x = (const float*)d_in[0];
    const float* Wm = (const float*)d_in[1];
    const float* bv = (const float*)d_in[2];
    const int* t = (const int*)d_in[3];
    float* out = (float*)d_out;

    // ws layout: [u ping-pong: NB*PLANE f][partA: NB*3*GBLK f]
    //            [stepPart: NSTEPS*NB*GBLK f][bar: NB u32]
    float* wsU = (float*)d_ws;
    float* partA = wsU + (size_t)NB * PLANE;
    float* stepPart = partA + NB * 3 * GBLK;
    unsigned* bar = (unsigned*)(stepPart + NSTEPS * NB * GBLK);

    // Only the barrier counters need zeroing (ws is poisoned each call);
    // every partial-sum slot is written before it is read.
    (void)hipMemsetAsync(bar, 0, sizeof(unsigned) * NB, stream);

    fused_kernel<<<NBLOCKS, 256, 0, stream>>>(x, out, wsU, partA, stepPart, bar,
                                              Wm, bv, t);
}

// Round 6
// 530.181 us; speedup vs baseline: 2.3804x; 1.2287x over previous
//
#include <hip/hip_runtime.h>
#include <cstddef>

#define NB 32
#define NC 4
#define NH 512
#define NW 512
#define PLANE (NH * NW)
#define NSTEPS 8
#define GBLK 32                 // blocks per batch (one barrier group)
#define SROWS (NH / GBLK)       // 16 rows per strip
#define NBLOCKS (NB * GBLK)     // 1024 blocks = 4/CU on 256 CUs -> all resident

typedef float v4f __attribute__((ext_vector_type(4)));

// ---- coherent-path (L3) accessors: relaxed agent-scope atomics bypass the
// ---- non-coherent per-XCD L2/L1. Used ONLY for strip edge rows + sums.
__device__ __forceinline__ float aloadf(const float* p) {
    return __hip_atomic_load(p, __ATOMIC_RELAXED, __HIP_MEMORY_SCOPE_AGENT);
}
__device__ __forceinline__ v4f aload4(const float* p) {
    const unsigned long long* q = (const unsigned long long*)p;
    union { unsigned long long u[2]; v4f v; } r;
    r.u[0] = __hip_atomic_load(q, __ATOMIC_RELAXED, __HIP_MEMORY_SCOPE_AGENT);
    r.u[1] = __hip_atomic_load(q + 1, __ATOMIC_RELAXED, __HIP_MEMORY_SCOPE_AGENT);
    return r.v;
}
__device__ __forceinline__ void astore4(float* p, v4f v) {
    union { v4f v; unsigned long long u[2]; } r; r.v = v;
    unsigned long long* q = (unsigned long long*)p;
    __hip_atomic_store(q, r.u[0], __ATOMIC_RELAXED, __HIP_MEMORY_SCOPE_AGENT);
    __hip_atomic_store(q + 1, r.u[1], __ATOMIC_RELAXED, __HIP_MEMORY_SCOPE_AGENT);
}
// Rows y with (y mod 16) in {0,15} are strip-edge rows: stored/loaded atomically.
__device__ __forceinline__ bool edgeRow(int y) {
    int r = y & (SROWS - 1);
    return (r == 0) | (r == SROWS - 1);
}

// Block-wide (256-thread) sum reduction. Valid result only in threadIdx.x==0.
__device__ __forceinline__ float blockReduce256(float v, float* sm) {
#pragma unroll
    for (int off = 32; off > 0; off >>= 1) v += __shfl_down(v, off, 64);
    int lane = threadIdx.x & 63;
    int wave = threadIdx.x >> 6;
    if (lane == 0) sm[wave] = v;
    __syncthreads();
    float r = (threadIdx.x == 0) ? ((sm[0] + sm[1]) + (sm[2] + sm[3])) : 0.0f;
    __syncthreads();
    return r;
}

// Fence-free barrier among the GBLK blocks of one batch.
// Round-5 lesson: per-block agent release/acquire fences = thousands of full
// L2 writebacks+invalidates (485us, VALUBusy 2%). Now ALL cross-block data
// rides relaxed agent atomics (coherent at L3), so the barrier needs no cache
// maintenance at all: __syncthreads drains every wave's vm ops to COMPLETION
// (compiler emits s_waitcnt vmcnt(0) before s_barrier), i.e. the edge-row
// atomic stores + partial-sum atomicAdds have reached the coherence point;
// then one relaxed fetch_add publishes and peers spin with relaxed loads.
// All 1024 blocks are co-resident (4/CU), so the spin cannot deadlock.
__device__ __forceinline__ void groupBarrier(unsigned* bar, unsigned tgt) {
    __syncthreads();
    if (threadIdx.x == 0) {
        __hip_atomic_fetch_add(bar, 1u, __ATOMIC_RELAXED, __HIP_MEMORY_SCOPE_AGENT);
        unsigned v;
        do {
            v = __hip_atomic_load(bar, __ATOMIC_RELAXED, __HIP_MEMORY_SCOPE_AGENT);
            if (v < tgt) __builtin_amdgcn_s_sleep(2);
        } while (v < tgt);
    }
    __syncthreads();
}

// One kernel for the whole op. Block (b, s) owns strip s of batch b forever.
// Phase A: strip sums of all 4 channels (atomicAdd) + nontemporal copy of
//          ch1..3 (and ch0 for t==0 batches, whose result IS the input).
// Phase B: t[b] steps, separated by per-batch fence-free groupBarrier.
//          Interior rows: normal ld/st (same block re-reads its own writes).
//          Edge rows (shared with neighbor strips): atomic ld/st via L3.
//          Final step writes directly to out ch0.
__global__ __launch_bounds__(256, 4) void fused_kernel(
    const float* __restrict__ x, float* __restrict__ out, float* __restrict__ ws,
    float* __restrict__ sumsAll,    // [NB][NC] ch sums (ch1..3 used)
    float* __restrict__ stepSums,   // [NSTEPS][NB] ch0 sum per step
    unsigned* __restrict__ bar,     // [NB] monotonic barrier counters (zeroed)
    const float* __restrict__ Wm, const float* __restrict__ bv,
    const int* __restrict__ tg) {
    __shared__ float sm[4];
    __shared__ float prm[2];
    int b = blockIdx.x >> 5;        // batch
    int s = blockIdx.x & 31;        // strip
    int tb = tg[b];

    const size_t xb = (size_t)b * NC * PLANE;
    const int rows0 = s * SROWS;
    const int nvec = SROWS * NW / 4;    // 2048 float4 per strip

    // ---------- Phase A ----------
    {
        const v4f* s4 = (const v4f*)(x + xb + (size_t)rows0 * NW);
        v4f* d4 = (v4f*)(out + xb + (size_t)rows0 * NW);
        float a0 = 0.0f;
        if (tb == 0) {
            for (int j = threadIdx.x; j < nvec; j += 256) {
                v4f v = s4[j];
                a0 += (v.x + v.y) + (v.z + v.w);
                __builtin_nontemporal_store(v, &d4[j]);   // final result = input
            }
        } else {
            for (int j = threadIdx.x; j < nvec; j += 256) {
                v4f v = s4[j];                             // re-read by step 0
                a0 += (v.x + v.y) + (v.z + v.w);
            }
        }
        float a123[3];
#pragma unroll
        for (int c = 1; c < 4; ++c) {
            const v4f* sc = (const v4f*)(x + xb + (size_t)c * PLANE + (size_t)rows0 * NW);
            v4f* dc = (v4f*)(out + xb + (size_t)c * PLANE + (size_t)rows0 * NW);
            float a = 0.0f;
            for (int j = threadIdx.x; j < nvec; j += 256) {
                v4f v = __builtin_nontemporal_load(&sc[j]);
                a += (v.x + v.y) + (v.z + v.w);
                __builtin_nontemporal_store(v, &dc[j]);
            }
            a123[c - 1] = a;
        }
        float t0 = blockReduce256(a0, sm);
        float t1 = blockReduce256(a123[0], sm);
        float t2 = blockReduce256(a123[1], sm);
        float t3 = blockReduce256(a123[2], sm);
        if (threadIdx.x == 0) {
            atomicAdd(&stepSums[b], t0);                   // step-0 ch0 sum
            atomicAdd(&sumsAll[b * NC + 1], t1);
            atomicAdd(&sumsAll[b * NC + 2], t2);
            atomicAdd(&sumsAll[b * NC + 3], t3);
        }
    }
    if (tb == 0) return;

    unsigned gen = 1;
    groupBarrier(&bar[b], GBLK * gen);

    // ch1..3 statics: load ONCE into thread-0 registers (constant across steps).
    float zc0 = 0.0f, zc1 = 0.0f;
    if (threadIdx.x == 0) {
        const float inv = 1.0f / (float)PLANE;
        float f1 = aloadf(&sumsAll[b * NC + 1]) * inv;
        float f2 = aloadf(&sumsAll[b * NC + 2]) * inv;
        float f3 = aloadf(&sumsAll[b * NC + 3]) * inv;
        zc0 = f1 * Wm[2] + f2 * Wm[4] + f3 * Wm[6] + bv[0];
        zc1 = f1 * Wm[3] + f2 * Wm[5] + f3 * Wm[7] + bv[1];
    }

    const int col4 = threadIdx.x & 127;
    const int x0 = col4 * 4;
    const int half = threadIdx.x >> 7;
    const int lane = threadIdx.x & 63;
    const int y0 = rows0 + half * (SROWS / 2);

    // ---------- Phase B ----------
    for (int i = 0; i < tb; ++i) {
        if (threadIdx.x == 0) {
            float f0 = aloadf(&stepSums[i * NB + b]) * (1.0f / (float)PLANE);
            float z0 = f0 * Wm[0] + zc0;
            float z1 = f0 * Wm[1] + zc1;
            prm[0] = 0.2f / (1.0f + expf(-z0));        // D
            prm[1] = 0.1f / (1.0f + expf(-z1));        // rho
        }
        __syncthreads();
        float D = prm[0], rho = prm[1];

        const float* sp = (i == 0) ? (x + xb)
                        : (i & 1)  ? (ws + (size_t)b * PLANE)
                                   : (out + xb);
        bool fin = (i == tb - 1);
        float* dp = (fin || (i & 1)) ? (out + xb) : (ws + (size_t)b * PLANE);

        int yu = (y0 - 1) & (NH - 1);
        v4f up = edgeRow(yu) ? aload4(sp + (size_t)yu * NW + x0)
                             : *(const v4f*)(sp + (size_t)yu * NW + x0);
        v4f cc = edgeRow(y0) ? aload4(sp + (size_t)y0 * NW + x0)
                             : *(const v4f*)(sp + (size_t)y0 * NW + x0);
        float acc = 0.0f;
#pragma unroll
        for (int k = 0; k < SROWS / 2; ++k) {
            int y = y0 + k;
            int yd = (y + 1) & (NH - 1);
            v4f dn = edgeRow(yd) ? aload4(sp + (size_t)yd * NW + x0)
                                 : *(const v4f*)(sp + (size_t)yd * NW + x0);
            bool eC = edgeRow(y);
            // Row halos: col4 = lane + 64*w is consecutive within a wave.
            float lft = __shfl_up(cc.w, 1, 64);
            if (lane == 0) {
                const float* p = sp + (size_t)y * NW + ((x0 - 1) & (NW - 1));
                lft = eC ? aloadf(p) : *p;
            }
            float rgt = __shfl_down(cc.x, 1, 64);
            if (lane == 63) {
                const float* p = sp + (size_t)y * NW + ((x0 + 4) & (NW - 1));
                rgt = eC ? aloadf(p) : *p;
            }
            v4f un;
            un.x = cc.x + (D * (up.x + dn.x + lft + cc.y - 4.0f * cc.x) + rho * cc.x * (1.0f - cc.x));
            un.y = cc.y + (D * (up.y + dn.y + cc.x + cc.z - 4.0f * cc.y) + rho * cc.y * (1.0f - cc.y));
            un.z = cc.z + (D * (up.z + dn.z + cc.y + cc.w - 4.0f * cc.z) + rho * cc.z * (1.0f - cc.z));
            un.w = cc.w + (D * (up.w + dn.w + cc.z + rgt - 4.0f * cc.w) + rho * cc.w * (1.0f - cc.w));
            float* q = dp + (size_t)y * NW + x0;
            if (eC) astore4(q, un);
            else if (fin) __builtin_nontemporal_store(un, (v4f*)q);
            else *(v4f*)q = un;
            acc += (un.x + un.y) + (un.z + un.w);
            up = cc; cc = dn;
        }

        if (!fin) {
            float tot = blockReduce256(acc, sm);
            if (threadIdx.x == 0) atomicAdd(&stepSums[(i + 1) * NB + b], tot);
            ++gen;
            groupBarrier(&bar[b], GBLK * gen);
        }
    }
}

extern "C" void kernel_launch(void* const* d_in, const int* in_sizes, int n_in,
                              void* d_out, int out_size, void* d_ws, size_t ws_size,
                              hipStream_t stream) {
    const float* x = (const float*)d_in[0];
    const float* Wm = (const float*)d_in[1];
    const float* bv = (const float*)d_in[2];
    const int* t = (const int*)d_in[3];
    float* out = (float*)d_out;

    // ws layout: [u ping-pong: NB*PLANE f][sumsAll: NB*NC f]
    //            [stepSums: NSTEPS*NB f][bar: NB u32]
    float* wsU = (float*)d_ws;
    float* sumsAll = wsU + (size_t)NB * PLANE;
    float* stepSums = sumsAll + NB * NC;
    unsigned* bar = (unsigned*)(stepSums + NSTEPS * NB);

    // Zero accumulators + barrier counters (ws is poisoned each call).
    (void)hipMemsetAsync(sumsAll, 0,
                         sizeof(float) * (NB * NC + NSTEPS * NB) + sizeof(unsigned) * NB,
                         stream);

    fused_kernel<<<NBLOCKS, 256, 0, stream>>>(x, out, wsU, sumsAll, stepSums, bar,
                                              Wm, bv, t);
}

// Round 7
// 374.161 us; speedup vs baseline: 3.3729x; 1.4170x over previous
//
#include <hip/hip_runtime.h>
#include <cstddef>

#define NB 32
#define NC 4
#define NH 512
#define NW 512
#define PLANE (NH * NW)
#define NSTEPS 8
#define GBLK 16                 // blocks per batch (one barrier group)
#define SROWS (NH / GBLK)       // 32 rows per strip
#define NBLOCKS (NB * GBLK)     // 512 blocks -> 2/CU, co-resident by 4/CU bound

typedef float v4f __attribute__((ext_vector_type(4)));

// ---- coherent-path (L3) accessors: relaxed agent-scope atomics bypass the
// ---- non-coherent per-XCD L2/L1. Used ONLY for strip edge rows + sums.
__device__ __forceinline__ float aloadf(const float* p) {
    return __hip_atomic_load(p, __ATOMIC_RELAXED, __HIP_MEMORY_SCOPE_AGENT);
}
__device__ __forceinline__ v4f aload4(const float* p) {
    const unsigned long long* q = (const unsigned long long*)p;
    union { unsigned long long u[2]; v4f v; } r;
    r.u[0] = __hip_atomic_load(q, __ATOMIC_RELAXED, __HIP_MEMORY_SCOPE_AGENT);
    r.u[1] = __hip_atomic_load(q + 1, __ATOMIC_RELAXED, __HIP_MEMORY_SCOPE_AGENT);
    return r.v;
}
__device__ __forceinline__ void astore4(float* p, v4f v) {
    union { v4f v; unsigned long long u[2]; } r; r.v = v;
    unsigned long long* q = (unsigned long long*)p;
    __hip_atomic_store(q, r.u[0], __ATOMIC_RELAXED, __HIP_MEMORY_SCOPE_AGENT);
    __hip_atomic_store(q + 1, r.u[1], __ATOMIC_RELAXED, __HIP_MEMORY_SCOPE_AGENT);
}
__device__ __forceinline__ bool edgeRow(int y) {
    int r = y & (SROWS - 1);
    return (r == 0) | (r == SROWS - 1);
}
// Edge rows of the ws ping-pong planes are ONLY ever touched atomically (they
// never enter L1/L2, so plain vs atomic never mixes). x is immutable -> step 0
// (src == x) uses plain cached loads even for edges.
__device__ __forceinline__ v4f ldrow(const float* sp, int y, int x0, bool coh) {
    const float* p = sp + (size_t)y * NW + x0;
    return (coh && edgeRow(y)) ? aload4(p) : *(const v4f*)p;
}
__device__ __forceinline__ float ldsc(const float* sp, int y, int xx, bool coh) {
    const float* p = sp + (size_t)y * NW + xx;
    return (coh && edgeRow(y)) ? aloadf(p) : *p;
}

// Block-wide (256-thread) sum reduction. Valid result only in threadIdx.x==0.
__device__ __forceinline__ float blockReduce256(float v, float* sm) {
#pragma unroll
    for (int off = 32; off > 0; off >>= 1) v += __shfl_down(v, off, 64);
    int lane = threadIdx.x & 63;
    int wave = threadIdx.x >> 6;
    if (lane == 0) sm[wave] = v;
    __syncthreads();
    float r = (threadIdx.x == 0) ? ((sm[0] + sm[1]) + (sm[2] + sm[3])) : 0.0f;
    __syncthreads();
    return r;
}

// Fence-free barrier among the GBLK blocks of one batch (round-6 protocol:
// all cross-block data rides relaxed agent atomics, so no cache maintenance).
// __syncthreads drains vmcnt to 0 -> edge stores + sum adds are complete at
// the coherence point before the fetch_add publishes. bar slots are padded to
// one 128B line each so batches don't serialize on shared atomic lines.
__device__ __forceinline__ void groupBarrier(unsigned* bar, unsigned tgt) {
    __syncthreads();
    if (threadIdx.x == 0) {
        __hip_atomic_fetch_add(bar, 1u, __ATOMIC_RELAXED, __HIP_MEMORY_SCOPE_AGENT);
        unsigned v;
        do {
            v = __hip_atomic_load(bar, __ATOMIC_RELAXED, __HIP_MEMORY_SCOPE_AGENT);
            if (v < tgt) __builtin_amdgcn_s_sleep(2);
        } while (v < tgt);
    }
    __syncthreads();
}

// Layout paddings (atomic-line isolation).
#define SUMS_STRIDE 16          // sumsAll[b*16 + c]
#define STEP_STRIDE 16          // stepSums[(i*NB+b)*16]
#define BAR_STRIDE 32           // bar[b*32]

// One kernel. Block (b,s) owns strip s (32 rows) of batch b.
// Phase A (tb>0 only): channel-interleaved strip sums (4 independent loads in
//          flight), NT for ch1..3 (read again by the stolen copy), plain for
//          ch0 (re-read by step 0 from L2).
// Phase B: t[b] steps over ws plane ping-pong (never in-place; out is written
//          once, at the final step, with NT). Edge rows via relaxed atomics.
// Tail:    blocks done with their batch steal ch1..3 copy chunks from a global
//          counter -> the 200 MB copy overlaps other batches' barrier waits.
__global__ __launch_bounds__(256, 4) void fused_kernel(
    const float* __restrict__ x, float* __restrict__ out,
    float* __restrict__ wsA, float* __restrict__ wsB,
    float* __restrict__ sumsAll, float* __restrict__ stepSums,
    unsigned* __restrict__ bar, unsigned* __restrict__ copyCtr,
    const float* __restrict__ Wm, const float* __restrict__ bv,
    const int* __restrict__ tg) {
    __shared__ float sm[4];
    __shared__ float prm[2];
    __shared__ unsigned cidSh;
    int b = blockIdx.x >> 4;        // batch
    int s = blockIdx.x & 15;        // strip
    int tb = tg[b];

    const size_t xb = (size_t)b * NC * PLANE;
    const int rows0 = s * SROWS;
    const int npt = SROWS * NW / 4 / 256;   // 16 v4f per thread per channel

    if (tb > 0) {
        // ---------- Phase A: sums only ----------
        const v4f* c0 = (const v4f*)(x + xb + (size_t)rows0 * NW);
        const v4f* c1 = (const v4f*)(x + xb + (size_t)PLANE + (size_t)rows0 * NW);
        const v4f* c2 = (const v4f*)(x + xb + (size_t)2 * PLANE + (size_t)rows0 * NW);
        const v4f* c3 = (const v4f*)(x + xb + (size_t)3 * PLANE + (size_t)rows0 * NW);
        float a0 = 0.0f, a1 = 0.0f, a2 = 0.0f, a3 = 0.0f;
#pragma unroll 4
        for (int it = 0; it < npt; ++it) {
            int j = threadIdx.x + it * 256;
            v4f v0 = c0[j];                                 // cached: step 0 reuse
            v4f v1 = __builtin_nontemporal_load(&c1[j]);
            v4f v2 = __builtin_nontemporal_load(&c2[j]);
            v4f v3 = __builtin_nontemporal_load(&c3[j]);
            a0 += (v0.x + v0.y) + (v0.z + v0.w);
            a1 += (v1.x + v1.y) + (v1.z + v1.w);
            a2 += (v2.x + v2.y) + (v2.z + v2.w);
            a3 += (v3.x + v3.y) + (v3.z + v3.w);
        }
        float t0 = blockReduce256(a0, sm);
        float t1 = blockReduce256(a1, sm);
        float t2 = blockReduce256(a2, sm);
        float t3 = blockReduce256(a3, sm);
        if (threadIdx.x == 0) {
            atomicAdd(&stepSums[b * STEP_STRIDE], t0);      // step-0 ch0 sum
            atomicAdd(&sumsAll[b * SUMS_STRIDE + 1], t1);
            atomicAdd(&sumsAll[b * SUMS_STRIDE + 2], t2);
            atomicAdd(&sumsAll[b * SUMS_STRIDE + 3], t3);
        }

        unsigned gen = 1;
        groupBarrier(&bar[b * BAR_STRIDE], GBLK * gen);

        // ch1..3 statics + Wm row 0: load ONCE into thread-0 registers.
        float zc0 = 0.0f, zc1 = 0.0f, w00 = 0.0f, w01 = 0.0f;
        if (threadIdx.x == 0) {
            const float inv = 1.0f / (float)PLANE;
            float f1 = aloadf(&sumsAll[b * SUMS_STRIDE + 1]) * inv;
            float f2 = aloadf(&sumsAll[b * SUMS_STRIDE + 2]) * inv;
            float f3 = aloadf(&sumsAll[b * SUMS_STRIDE + 3]) * inv;
            zc0 = f1 * Wm[2] + f2 * Wm[4] + f3 * Wm[6] + bv[0];
            zc1 = f1 * Wm[3] + f2 * Wm[5] + f3 * Wm[7] + bv[1];
            w00 = Wm[0]; w01 = Wm[1];
        }

        const int col4 = threadIdx.x & 127;
        const int x0 = col4 * 4;
        const int half = threadIdx.x >> 7;
        const int lane = threadIdx.x & 63;
        const int y0 = rows0 + half * (SROWS / 2);   // 16 rows per thread
        float* wsAb = wsA + (size_t)b * PLANE;
        float* wsBb = wsB + (size_t)b * PLANE;

        // ---------- Phase B ----------
        for (int i = 0; i < tb; ++i) {
            if (threadIdx.x == 0) {
                float f0 = aloadf(&stepSums[(i * NB + b) * STEP_STRIDE]) *
                           (1.0f / (float)PLANE);
                prm[0] = 0.2f / (1.0f + expf(-(f0 * w00 + zc0)));   // D
                prm[1] = 0.1f / (1.0f + expf(-(f0 * w01 + zc1)));   // rho
            }
            __syncthreads();
            float D = prm[0], rho = prm[1];

            bool fin = (i == tb - 1);
            const float* sp = (i == 0) ? (x + xb) : ((i & 1) ? wsAb : wsBb);
            float* dp = fin ? (out + xb) : ((i & 1) ? wsBb : wsAb);
            bool coh = (i != 0);            // x is immutable -> plain edge loads

            int yu = (y0 - 1) & (NH - 1);
            v4f up = ldrow(sp, yu, x0, coh);
            v4f cc = ldrow(sp, y0, x0, coh);
            float acc = 0.0f;
#pragma unroll
            for (int k = 0; k < SROWS / 2; ++k) {
                int y = y0 + k;
                int yd = (y + 1) & (NH - 1);
                v4f dn = ldrow(sp, yd, x0, coh);
                // Row halos: col4 = lane + 64*w is consecutive within a wave.
                float lft = __shfl_up(cc.w, 1, 64);
                if (lane == 0) lft = ldsc(sp, y, (x0 - 1) & (NW - 1), coh);
                float rgt = __shfl_down(cc.x, 1, 64);
                if (lane == 63) rgt = ldsc(sp, y, (x0 + 4) & (NW - 1), coh);
                v4f un;
                un.x = cc.x + (D * (up.x + dn.x + lft + cc.y - 4.0f * cc.x) + rho * cc.x * (1.0f - cc.x));
                un.y = cc.y + (D * (up.y + dn.y + cc.x + cc.z - 4.0f * cc.y) + rho * cc.y * (1.0f - cc.y));
                un.z = cc.z + (D * (up.z + dn.z + cc.y + cc.w - 4.0f * cc.z) + rho * cc.z * (1.0f - cc.z));
                un.w = cc.w + (D * (up.w + dn.w + cc.z + rgt - 4.0f * cc.w) + rho * cc.w * (1.0f - cc.w));
                float* q = dp + (size_t)y * NW + x0;
                if (fin) __builtin_nontemporal_store(un, (v4f*)q);
                else if (edgeRow(y)) astore4(q, un);
                else *(v4f*)q = un;
                acc += (un.x + un.y) + (un.z + un.w);
                up = cc; cc = dn;
            }

            if (!fin) {
                float tot = blockReduce256(acc, sm);
                if (threadIdx.x == 0)
                    atomicAdd(&stepSums[((i + 1) * NB + b) * STEP_STRIDE], tot);
                ++gen;
                groupBarrier(&bar[b * BAR_STRIDE], GBLK * gen);
            }
        }
    } else {
        // tb == 0: out ch0 = x ch0 (no sums needed for this batch).
        const v4f* s4 = (const v4f*)(x + xb + (size_t)rows0 * NW);
        v4f* d4 = (v4f*)(out + xb + (size_t)rows0 * NW);
#pragma unroll 4
        for (int it = 0; it < npt; ++it) {
            int j = threadIdx.x + it * 256;
            __builtin_nontemporal_store(__builtin_nontemporal_load(&s4[j]), &d4[j]);
        }
    }

    // ---------- Tail: work-steal the ch1..3 copy (3*NB*GBLK chunks) ----------
    const unsigned NCHUNK = 3u * NB * GBLK;
    for (;;) {
        if (threadIdx.x == 0) cidSh = atomicAdd(copyCtr, 1u);
        __syncthreads();
        unsigned cid = cidSh;
        __syncthreads();
        if (cid >= NCHUNK) break;
        int c = 1 + (int)(cid / (NB * GBLK));
        int r = (int)(cid % (NB * GBLK));
        int cb = r >> 4, cs = r & 15;
        size_t base = ((size_t)cb * NC + c) * PLANE + (size_t)(cs * SROWS) * NW;
        const v4f* s4 = (const v4f*)(x + base);
        v4f* d4 = (v4f*)(out + base);
#pragma unroll 4
        for (int it = 0; it < npt; ++it) {
            int j = threadIdx.x + it * 256;
            __builtin_nontemporal_store(__builtin_nontemporal_load(&s4[j]), &d4[j]);
        }
    }
}

extern "C" void kernel_launch(void* const* d_in, const int* in_sizes, int n_in,
                              void* d_out, int out_size, void* d_ws, size_t ws_size,
                              hipStream_t stream) {
    const float* x = (const float*)d_in[0];
    const float* Wm = (const float*)d_in[1];
    const float* bv = (const float*)d_in[2];
    const int* t = (const int*)d_in[3];
    float* out = (float*)d_out;

    // ws layout: [wsA: NB*PLANE f][wsB: NB*PLANE f][sumsAll: NB*16 f]
    //            [stepSums: NSTEPS*NB*16 f][bar: NB*32 u32][copyCtr: 1 u32]
    float* wsA = (float*)d_ws;
    float* wsB = wsA + (size_t)NB * PLANE;
    float* sumsAll = wsB + (size_t)NB * PLANE;
    float* stepSums = sumsAll + NB * SUMS_STRIDE;
    unsigned* bar = (unsigned*)(stepSums + NSTEPS * NB * STEP_STRIDE);
    unsigned* copyCtr = bar + NB * BAR_STRIDE;

    // Zero accumulators + barrier counters + steal counter (ws is poisoned).
    size_t zbytes = sizeof(float) * (NB * SUMS_STRIDE + NSTEPS * NB * STEP_STRIDE) +
                    sizeof(unsigned) * (NB * BAR_STRIDE + 1);
    (void)hipMemsetAsync(sumsAll, 0, zbytes, stream);

    fused_kernel<<<NBLOCKS, 256, 0, stream>>>(x, out, wsA, wsB, sumsAll, stepSums,
                                              bar, copyCtr, Wm, bv, t);
}